// Round 6
// baseline (285.584 us; speedup 1.0000x reference)
//
#include <hip/hip_runtime.h>
#include <cstdint>

#define TOK 16384
#define HD 2048
#define NE 64
#define HQ 512
#define KC 64                  // k per chunk
#define NCH (HD / KC)          // 32 chunks
#define ESCALE 1073741824.0f   // 2^30
#define STB 512                // selthr block size

// ---------------------------------------------------------------------------
// K1: router logits = hid @ rw^T (f32, full K per block) + fused colsum.
// 256 thr = 4 waves; tile 64 tok x 64 exp. lane = token, wave = 16 experts,
// acc[16] per thread. A: per-lane swizzled ds_read_b128 (1 per k-quad,
// reused for 16 experts). B: wave-uniform ds_read_b128 (broadcast, imm
// offsets, ~no LDS bandwidth). Grid 256 = 1 block/CU. LDS 66 KB.
// No k-split, no atomics: logits direct to d_out, colsum partials to csP.
// ---------------------------------------------------------------------------
__global__ __launch_bounds__(256) void k_router(const float* __restrict__ hid,
                                                const float* __restrict__ rw,
                                                float* __restrict__ logits,
                                                float* __restrict__ csP) {
  __shared__ __align__(16) float As[2][64][KC];   // 32 KB
  __shared__ __align__(16) float Bs[2][64][KC];   // 32 KB
  __shared__ float red[2][4][64];                 // 2 KB
  const int tid = threadIdx.x;
  const int lane = tid & 63;
  const int w = tid >> 6;
  const int t0 = blockIdx.x * 64;
  const int e0 = w * 16;
  // staging: thread stages 64 B of one A row and one B row per chunk
  const int srow = tid >> 2;            // 0..63 (A token row / B expert row)
  const int sc4 = (tid & 3) * 4;        // first of 4 staged float4 slots
  const float* ha = hid + (size_t)(t0 + srow) * HD + sc4 * 4;
  const float* ba = rw + (size_t)srow * HD + sc4 * 4;
  int soff[4];
#pragma unroll
  for (int j = 0; j < 4; ++j) {
    const int c4 = sc4 + j;
    soff[j] = ((c4 & 8) | ((c4 & 7) ^ (srow & 7))) << 2;  // float offset in row
  }
  float4 pa[4], pb[4];
#pragma unroll
  for (int j = 0; j < 4; ++j) {
    pa[j] = *(const float4*)(ha + j * 4);
    pb[j] = *(const float4*)(ba + j * 4);
  }
  float acc[16];
#pragma unroll
  for (int e = 0; e < 16; ++e) acc[e] = 0.f;
  // per-lane A base (floats) with swizzle XOR folded in
  const int albase = lane * KC + ((lane & 7) << 2);
  // colsum assignment: thread sums column (tid&63) over rows g*16..g*16+15
  const int colc = tid & 63, g = tid >> 6;
  const int cc4 = colc >> 2, csub = colc & 3;

  for (int c = 0; c < NCH; ++c) {
    const int cur = c & 1;
    float* Asc = &As[cur][0][0];
    float* Bsc = &Bs[cur][0][0];
#pragma unroll
    for (int j = 0; j < 4; ++j) {
      *(float4*)(Asc + srow * KC + soff[j]) = pa[j];
      *(float4*)(Bsc + srow * KC + soff[j]) = pb[j];
    }
    if (c + 1 < NCH) {
#pragma unroll
      for (int j = 0; j < 4; ++j) {
        pa[j] = *(const float4*)(ha + (c + 1) * KC + j * 4);
        pb[j] = *(const float4*)(ba + (c + 1) * KC + j * 4);
      }
    }
    __syncthreads();
    // flush previous chunk's colsum partial (plain coalesced store)
    if (c > 0 && tid < 64) {
      const int pbuf = cur ^ 1;
      float v = red[pbuf][0][tid] + red[pbuf][1][tid] +
                red[pbuf][2][tid] + red[pbuf][3][tid];
      csP[(size_t)blockIdx.x * HD + (c - 1) * KC + tid] = v;
    }
    // this chunk's colsum partial (2-way bank alias max = free)
    {
      float s = 0.f;
#pragma unroll
      for (int i = 0; i < 16; ++i) {
        const int row = g * 16 + i;
        s += Asc[row * KC + ((((cc4 & 8) | ((cc4 & 7) ^ (row & 7)))) << 2) + csub];
      }
      red[cur][g][colc] = s;
    }
    // compute: 16 k-quads x (1 per-lane A read + 16 uniform B reads + 64 FMA)
#pragma unroll
    for (int kq = 0; kq < 16; ++kq) {
      const float4 a = *(const float4*)(Asc + ((albase ^ ((kq & 7) << 2)) + ((kq & 8) << 2)));
#pragma unroll
      for (int e = 0; e < 16; ++e) {
        const float4 b = *(const float4*)(Bsc + (e0 + e) * KC +
                                          (((kq & 8) | ((kq & 7) ^ (e & 7))) << 2));
        acc[e] = fmaf(a.x, b.x, acc[e]);
        acc[e] = fmaf(a.y, b.y, acc[e]);
        acc[e] = fmaf(a.z, b.z, acc[e]);
        acc[e] = fmaf(a.w, b.w, acc[e]);
      }
    }
  }
  __syncthreads();
  // final colsum flush (chunk NCH-1 -> red[1])
  if (tid < 64) {
    float v = red[1][0][tid] + red[1][1][tid] + red[1][2][tid] + red[1][3][tid];
    csP[(size_t)blockIdx.x * HD + (NCH - 1) * KC + tid] = v;
  }
  // logits [t][e]: each thread writes its token row's 16-expert span (64 B)
  float* lrow = logits + (size_t)(t0 + lane) * NE + e0;
#pragma unroll
  for (int j = 0; j < 4; ++j)
    *(float4*)(lrow + j * 4) =
        make_float4(acc[4 * j], acc[4 * j + 1], acc[4 * j + 2], acc[4 * j + 3]);
}

// ---------------------------------------------------------------------------
// K1b: colsum[k] = sum over 256 blocks (fixed order, deterministic).
// ---------------------------------------------------------------------------
__global__ __launch_bounds__(256) void k_reduce_cs(const float* __restrict__ csP,
                                                   float* __restrict__ colsum) {
  __shared__ float rr[4][64];
  const int tid = threadIdx.x;
  const int k = blockIdx.x * 64 + (tid & 63);
  const int part = tid >> 6;
  float s = 0.f;
  for (int b = part * 64; b < part * 64 + 64; ++b)
    s += csP[(size_t)b * HD + k];
  rr[part][tid & 63] = s;
  __syncthreads();
  if (tid < 64)
    colsum[blockIdx.x * 64 + tid] = rr[0][tid] + rr[1][tid] + rr[2][tid] + rr[3][tid];
}

// ---------------------------------------------------------------------------
// K2a: h = relu(cap_w1 @ mean_h + b1), one block per output row.
// ---------------------------------------------------------------------------
__global__ __launch_bounds__(256) void k_cap1(const float* __restrict__ w1,
                                              const float* __restrict__ b1,
                                              const float* __restrict__ colsum,
                                              float* __restrict__ h) {
  const int row = blockIdx.x;
  const int tid = threadIdx.x;
  const float invB = 1.0f / 16384.0f;
  const float* wr = w1 + (size_t)row * HD;
  float4 a0 = *(const float4*)(wr + tid * 4);
  float4 a1 = *(const float4*)(wr + 1024 + tid * 4);
  float4 c0 = *(const float4*)(colsum + tid * 4);
  float4 c1 = *(const float4*)(colsum + 1024 + tid * 4);
  float s = a0.x * (c0.x * invB) + a0.y * (c0.y * invB) +
            a0.z * (c0.z * invB) + a0.w * (c0.w * invB) +
            a1.x * (c1.x * invB) + a1.y * (c1.y * invB) +
            a1.z * (c1.z * invB) + a1.w * (c1.w * invB);
#pragma unroll
  for (int off = 32; off; off >>= 1) s += __shfl_down(s, off);
  __shared__ float wsum[4];
  if ((tid & 63) == 0) wsum[tid >> 6] = s;
  __syncthreads();
  if (tid == 0) {
    float t = wsum[0] + wsum[1] + wsum[2] + wsum[3] + b1[row];
    h[row] = fmaxf(t, 0.f);
  }
}

// ---------------------------------------------------------------------------
// K2b+c fused: cap_logits = cap_w2 @ h + b2, softmax, clip, capacity.
// ---------------------------------------------------------------------------
__global__ __launch_bounds__(256) void k_caphead(const float* __restrict__ w2,
                                                 const float* __restrict__ b2,
                                                 const float* __restrict__ h,
                                                 int* __restrict__ cap) {
  __shared__ float clS[64];
  const int tid = threadIdx.x;
  const int e = tid >> 2, part = tid & 3;
  const float* wr = w2 + (size_t)e * HQ + part * 128;
  const float* hp = h + part * 128;
  float s = 0.f;
#pragma unroll
  for (int i = 0; i < 32; ++i) {
    float4 a = *(const float4*)(wr + i * 4);
    float4 hv = *(const float4*)(hp + i * 4);
    s += a.x * hv.x + a.y * hv.y + a.z * hv.z + a.w * hv.w;
  }
  s += __shfl_down(s, 1);
  s += __shfl_down(s, 2);
  if (part == 0) clS[e] = s + b2[e];
  __syncthreads();
  if (tid < 64) {
    float l = clS[tid];
    float m = l;
#pragma unroll
    for (int off = 1; off < 64; off <<= 1) m = fmaxf(m, __shfl_xor(m, off));
    float ex = expf(l - m);
    float sum = ex;
#pragma unroll
    for (int off = 1; off < 64; off <<= 1) sum += __shfl_xor(sum, off);
    float wgt = ex / sum;
    float cf = 1.25f + (wgt - 0.5f) * 1.0f;
    cf = fminf(fmaxf(cf, 1.0f), 2.0f);
    cap[tid] = (int)floorf(16384.0f * cf / 64.0f);
  }
}

// ---------------------------------------------------------------------------
// K3a: per-token softmax (reads logits [t][e] from d_out), writes probsT
// [e][t] via LDS transpose; entropy via int64 fixed-point atomic.
// ---------------------------------------------------------------------------
__global__ __launch_bounds__(256) void k_softmax(const float* __restrict__ logits,
                                                 float* __restrict__ probsT,
                                                 unsigned long long* __restrict__ ent) {
  __shared__ float tpT[64][65];
  __shared__ float sw[4];
  const int tid = threadIdx.x;
  const int lane = tid & 63;
  const int wv = tid >> 6;
  const int t0 = blockIdx.x * 64;
  const int tt = tid >> 2, q = tid & 3;
  const float* lr = logits + (size_t)(t0 + tt) * NE + q * 16;
  float4 v0 = *(const float4*)(lr);
  float4 v1 = *(const float4*)(lr + 4);
  float4 v2 = *(const float4*)(lr + 8);
  float4 v3 = *(const float4*)(lr + 12);
  float p[16] = {v0.x, v0.y, v0.z, v0.w, v1.x, v1.y, v1.z, v1.w,
                 v2.x, v2.y, v2.z, v2.w, v3.x, v3.y, v3.z, v3.w};
  float m = p[0];
#pragma unroll
  for (int i = 1; i < 16; ++i) m = fmaxf(m, p[i]);
  m = fmaxf(m, __shfl_xor(m, 1));
  m = fmaxf(m, __shfl_xor(m, 2));
  float s = 0.f;
#pragma unroll
  for (int i = 0; i < 16; ++i) { p[i] = expf(p[i] - m); s += p[i]; }
  s += __shfl_xor(s, 1);
  s += __shfl_xor(s, 2);
  const float inv = 1.0f / s;
  float el = 0.f;
#pragma unroll
  for (int i = 0; i < 16; ++i) {
    float pp = p[i] * inv;
    p[i] = pp;
    el += pp * logf(pp + 1e-8f);
  }
  el += __shfl_xor(el, 1);
  el += __shfl_xor(el, 2);
#pragma unroll
  for (int i = 0; i < 16; ++i) tpT[q * 16 + i][tt] = p[i];
  float ew = (q == 0) ? el : 0.f;
#pragma unroll
  for (int off = 4; off < 64; off <<= 1) ew += __shfl_xor(ew, off);
  if (lane == 0) sw[wv] = ew;
  __syncthreads();
  if (tid == 0) {
    float bt = sw[0] + sw[1] + sw[2] + sw[3];
    atomicAdd(ent, (unsigned long long)(long long)__float2ll_rn(bt * ESCALE));
  }
  const int er = tid >> 6, tl = tid & 63;
#pragma unroll
  for (int pass = 0; pass < 16; ++pass) {
    const int e = pass * 4 + er;
    probsT[(size_t)e * TOK + t0 + tl] = tpT[e][tl];
  }
}

// ---------------------------------------------------------------------------
// K3b: per-expert exact k-th largest prob: 3-pass radix select (2048-bin
// LDS hist, uint4 loads, parallel suffix scan), 512 thr, 1 block/expert.
// ---------------------------------------------------------------------------
__global__ __launch_bounds__(STB) void k_selthr(const float* __restrict__ probsT,
                                                const int* __restrict__ cap,
                                                unsigned* __restrict__ thrT,
                                                int* __restrict__ cutoff) {
  const int e = blockIdx.x, tid = threadIdx.x;
  const uint4* col4 = (const uint4*)(probsT + (size_t)e * TOK);
  const unsigned* col = (const unsigned*)(probsT + (size_t)e * TOK);
  __shared__ unsigned hist[2048];
  __shared__ int wsfx[STB];
  __shared__ unsigned sh_pref;
  __shared__ int sh_rem;
  __shared__ int sred[8], sgt[8], seq2[8];
  const int k = cap[e];
  unsigned prefix = 0, pmask = 0;
  int rem = k;
#pragma unroll
  for (int pass = 0; pass < 3; ++pass) {
    const int shift = (pass == 0) ? 21 : (pass == 1) ? 10 : 0;
    const int nb = (pass == 2) ? 1024 : 2048;
    const unsigned bmask = nb - 1;
    for (int i = tid; i < nb; i += STB) hist[i] = 0;
    __syncthreads();
    for (int it = 0; it < TOK / (4 * STB); ++it) {
      uint4 v = col4[it * STB + tid];
      if ((v.x & pmask) == prefix) atomicAdd(&hist[(v.x >> shift) & bmask], 1u);
      if ((v.y & pmask) == prefix) atomicAdd(&hist[(v.y >> shift) & bmask], 1u);
      if ((v.z & pmask) == prefix) atomicAdd(&hist[(v.z >> shift) & bmask], 1u);
      if ((v.w & pmask) == prefix) atomicAdd(&hist[(v.w >> shift) & bmask], 1u);
    }
    __syncthreads();
    const int cs = nb / STB;
    const int base = tid * cs;
    int s = 0;
    for (int m2 = 0; m2 < cs; ++m2) s += (int)hist[base + m2];
    wsfx[tid] = s;
    __syncthreads();
    for (int off = 1; off < STB; off <<= 1) {
      int v = (tid + off < STB) ? wsfx[tid + off] : 0;
      __syncthreads();
      wsfx[tid] += v;
      __syncthreads();
    }
    int r = (tid < STB - 1) ? wsfx[tid + 1] : 0;
    for (int m2 = cs - 1; m2 >= 0; --m2) {
      int rb = r + (int)hist[base + m2];
      if (rb >= rem && r < rem) {
        sh_pref = prefix | ((unsigned)(base + m2) << shift);
        sh_rem = rem - r;
      }
      r = rb;
    }
    __syncthreads();
    prefix = sh_pref;
    rem = sh_rem;
    pmask |= bmask << shift;
    __syncthreads();
  }
  const unsigned T = prefix;
  int lgt = 0, leq = 0;
  for (int it = 0; it < TOK / (4 * STB); ++it) {
    uint4 v = col4[it * STB + tid];
    lgt += (v.x > T) + (v.y > T) + (v.z > T) + (v.w > T);
    leq += (v.x == T) + (v.y == T) + (v.z == T) + (v.w == T);
  }
#pragma unroll
  for (int off = 32; off; off >>= 1) {
    lgt += __shfl_down(lgt, off);
    leq += __shfl_down(leq, off);
  }
  if ((tid & 63) == 0) { sgt[tid >> 6] = lgt; seq2[tid >> 6] = leq; }
  __syncthreads();
  int c_gt = 0, c_eq = 0;
#pragma unroll
  for (int i = 0; i < 8; ++i) { c_gt += sgt[i]; c_eq += seq2[i]; }
  const int n_allowed = k - c_gt;
  int cut;
  if (n_allowed <= 0) {
    cut = -1;
  } else if (c_eq <= n_allowed) {
    cut = 0x7fffffff;
  } else {
    int lo = 0, hi = TOK - 1;
    while (lo < hi) {
      const int mid = (lo + hi) >> 1;
      int c = 0;
      for (int i = tid; i <= mid; i += STB) c += (col[i] == T);
#pragma unroll
      for (int off = 32; off; off >>= 1) c += __shfl_down(c, off);
      __syncthreads();
      if ((tid & 63) == 0) sred[tid >> 6] = c;
      __syncthreads();
      int cnt = 0;
#pragma unroll
      for (int i = 0; i < 8; ++i) cnt += sred[i];
      if (cnt >= n_allowed) hi = mid; else lo = mid + 1;
    }
    cut = lo;
  }
  if (tid == 0) { thrT[e] = T; cutoff[e] = cut; }
}

// ---------------------------------------------------------------------------
// K3c: per-token selection + weight + entropy finalize.
// ---------------------------------------------------------------------------
__global__ __launch_bounds__(256) void k_final(const float* __restrict__ probsT,
                                               const unsigned* __restrict__ thrT,
                                               const int* __restrict__ cutoff,
                                               const unsigned long long* __restrict__ ent,
                                               float* __restrict__ out_sel,
                                               float* __restrict__ out_w,
                                               float* __restrict__ out_ent) {
  __shared__ float tp[64][65];
  __shared__ unsigned sT[64];
  __shared__ int sC[64];
  const int tid = threadIdx.x;
  const int t0 = blockIdx.x * 64;
  if (tid < 64) { sT[tid] = thrT[tid]; sC[tid] = cutoff[tid]; }
  const int er = tid >> 6, tl2 = tid & 63;
#pragma unroll
  for (int pass = 0; pass < 16; ++pass) {
    const int e = pass * 4 + er;
    tp[e][tl2] = probsT[(size_t)e * TOK + t0 + tl2];
  }
  __syncthreads();
  const int tl = tid >> 2, q = tid & 3;
  const int t_abs = t0 + tl;
  int best = -1;
  float bw = 0.f;
  for (int i = 15; i >= 0; --i) {
    const int e = q * 16 + i;
    const float p = tp[e][tl];
    const unsigned v = __float_as_uint(p);
    const unsigned T = sT[e];
    if (v > T || (v == T && t_abs <= sC[e])) { best = e; bw = p; break; }
  }
#pragma unroll
  for (int off = 1; off <= 2; off <<= 1) {
    const int b2 = __shfl_xor(best, off);
    const float w2 = __shfl_xor(bw, off);
    if (b2 > best) { best = b2; bw = w2; }
  }
  if (q == 0) {
    out_sel[t_abs] = (float)(best >= 0 ? best : 0);
    out_w[t_abs] = (best >= 0 ? bw : 0.0f);
  }
  if (blockIdx.x == 0 && tid == 0)
    out_ent[0] = -((float)(long long)ent[0] * (1.0f / ESCALE)) / 16384.0f;
}

// ---------------------------------------------------------------------------
extern "C" void kernel_launch(void* const* d_in, const int* in_sizes, int n_in,
                              void* d_out, int out_size, void* d_ws, size_t ws_size,
                              hipStream_t stream) {
  (void)in_sizes; (void)n_in; (void)out_size; (void)ws_size;
  const float* hid = (const float*)d_in[0];
  const float* rw  = (const float*)d_in[1];
  const float* w1  = (const float*)d_in[2];
  const float* b1  = (const float*)d_in[3];
  const float* w2  = (const float*)d_in[4];
  const float* b2  = (const float*)d_in[5];
  float* out = (float*)d_out;
  float* logits  = out;
  float* out_sel = out + (size_t)TOK * NE;
  float* out_w   = out_sel + TOK;
  float* out_ent = out_w + TOK;
  char* ws = (char*)d_ws;
  float*              colsum = (float*)(ws + 0);        // 2048 f32
  unsigned long long* ent    = (unsigned long long*)(ws + 8192);
  float*              h      = (float*)(ws + 8448);     // 512 f32
  int*                cap    = (int*)(ws + 10752);
  unsigned*           thr    = (unsigned*)(ws + 11008);
  int*                cut    = (int*)(ws + 11264);
  // region X (4 MiB): csP (256 blocks x 2048 = 2 MB; K1 -> K1b) then probsT
  // (4 MB; K3a -> K3b/K3c). Stream-ordered reuse, no overlap.
  float*              csP    = (float*)(ws + 16384);
  float*              probsT = (float*)(ws + 16384);

  hipMemsetAsync(ent, 0, 8, stream);
  hipLaunchKernelGGL(k_router, dim3(TOK / 64), dim3(256), 0, stream,
                     hid, rw, logits, csP);
  hipLaunchKernelGGL(k_reduce_cs, dim3(HD / 64), dim3(256), 0, stream, csP, colsum);
  hipLaunchKernelGGL(k_cap1, dim3(HQ), dim3(256), 0, stream, w1, b1, colsum, h);
  hipLaunchKernelGGL(k_caphead, dim3(1), dim3(256), 0, stream, w2, b2, h, cap);
  hipLaunchKernelGGL(k_softmax, dim3(TOK / 64), dim3(256), 0, stream,
                     logits, probsT, ent);
  hipLaunchKernelGGL(k_selthr, dim3(NE), dim3(STB), 0, stream, probsT, cap, thr, cut);
  hipLaunchKernelGGL(k_final, dim3(TOK / 64), dim3(256), 0, stream,
                     probsT, thr, cut, ent, out_sel, out_w, out_ent);
}

// Round 7
// 167.863 us; speedup vs baseline: 1.7013x; 1.7013x over previous
//
#include <hip/hip_runtime.h>
#include <cstdint>

#define TOK 16384
#define HD 2048
#define NE 64
#define HQ 512
#define KC 64                  // k per chunk
#define NCH (HD / KC)          // 32 chunks
#define ESCALE 1073741824.0f   // 2^30
#define STB 512                // selthr block size

// ---------------------------------------------------------------------------
// K1: router logits = hid @ rw^T (f32, full K) + fused colsum partials.
// R4 structure: 256 thr = 4 waves; tile 32 tok x 64 exp x 2048 k; wave tile
// 16x32; thread tile 2 tok x 4 exp (6 LDS reads : 32 FMA per k-quad).
// Grid 512 = 2 blocks/CU (grid-capped). LDS 50 KB.
// FIX vs R4: 16B-granularity XOR swizzle (R4's 32B version left half the
// bank groups cold -> 1.15e7 conflicts). A: slot=((q&7)^(row&7))|(q&8)
// (A rows differ in tm = low 3 bits); B: slot=((q&7)^((row>>2)&7))|(q&8)
// (B rows rB..rB+3 share (row>>2)&7 == tn). Every compute read: 8 distinct
// bank-quads x 8-way same-address broadcast = conflict-free.
// No k-split, no atomics: logits direct to d_out, colsum partials to csP.
// ---------------------------------------------------------------------------
__global__ __launch_bounds__(256, 2) void k_router(const float* __restrict__ hid,
                                                   const float* __restrict__ rw,
                                                   float* __restrict__ logits,
                                                   float* __restrict__ csP) {
  __shared__ __align__(16) float As[2][32][KC];   // 16 KB
  __shared__ __align__(16) float Bs[2][64][KC];   // 32 KB
  __shared__ float red[2][4][64];                 // 2 KB
  const int tid = threadIdx.x;
  const int lane = tid & 63;
  const int w = tid >> 6;
  const int tm = lane >> 3, tn = lane & 7;
  const int tsub = w >> 1, ehalf = w & 1;
  const int t0 = blockIdx.x * 32;
  // A staging: row = tid>>3 (0..31), slots ac0, ac0+1 (8 floats)
  const int arow = tid >> 3;
  const int ac0 = (tid & 7) * 2;
  const int aswz = arow & 7;
  const int aoff0 = ((((ac0 + 0) & 7) ^ aswz) | ((ac0 + 0) & 8)) << 2;
  const int aoff1 = ((((ac0 + 1) & 7) ^ aswz) | ((ac0 + 1) & 8)) << 2;
  const float* hap = hid + (size_t)(t0 + arow) * HD + ac0 * 4;
  // B staging: row = tid>>2 (0..63), slots bc0..bc0+3 (16 floats)
  const int brow = tid >> 2;
  const int bc0 = (tid & 3) * 4;
  const int bswz = (brow >> 2) & 7;
  int boff[4];
#pragma unroll
  for (int j = 0; j < 4; ++j) {
    const int cj = bc0 + j;
    boff[j] = (((cj & 7) ^ bswz) | (cj & 8)) << 2;
  }
  const float* bap = rw + (size_t)brow * HD + bc0 * 4;

  float4 pa0 = *(const float4*)(hap);
  float4 pa1 = *(const float4*)(hap + 4);
  float4 pb[4];
#pragma unroll
  for (int j = 0; j < 4; ++j) pb[j] = *(const float4*)(bap + j * 4);

  float acc[2][4];
#pragma unroll
  for (int i = 0; i < 2; ++i)
#pragma unroll
    for (int j = 0; j < 4; ++j) acc[i][j] = 0.f;

  const int rA = tsub * 16 + tm;        // token rows rA, rA+8 (both &7 == tm)
  const int rB = ehalf * 32 + tn * 4;   // expert rows rB..rB+3 ((r>>2)&7==tn)
  const int colc = tid & 63, g = tid >> 6;
  const int cc4 = colc >> 2, csub = colc & 3;

  for (int c = 0; c < NCH; ++c) {
    const int cur = c & 1;
    *(float4*)&As[cur][arow][aoff0] = pa0;
    *(float4*)&As[cur][arow][aoff1] = pa1;
#pragma unroll
    for (int j = 0; j < 4; ++j) *(float4*)&Bs[cur][brow][boff[j]] = pb[j];
    if (c + 1 < NCH) {
      pa0 = *(const float4*)(hap + (c + 1) * KC);
      pa1 = *(const float4*)(hap + (c + 1) * KC + 4);
#pragma unroll
      for (int j = 0; j < 4; ++j)
        pb[j] = *(const float4*)(bap + (c + 1) * KC + j * 4);
    }
    __syncthreads();
    // flush previous chunk's colsum partial (plain store, no atomics)
    if (c > 0 && tid < 64) {
      const int pbuf = cur ^ 1;
      float v = red[pbuf][0][tid] + red[pbuf][1][tid] +
                red[pbuf][2][tid] + red[pbuf][3][tid];
      csP[(size_t)blockIdx.x * HD + (c - 1) * KC + tid] = v;
    }
    // this chunk's colsum partial (swizzle-aware column reads, 2-way = free)
    {
      float s = 0.f;
#pragma unroll
      for (int i = 0; i < 8; ++i) {
        const int row = g * 8 + i;
        const int slot = (((cc4 & 7) ^ (row & 7)) | (cc4 & 8));
        s += As[cur][row][slot * 4 + csub];
      }
      red[cur][g][colc] = s;
    }
    // compute: 16 k-quads x (2 A + 4 B conflict-free b128 reads + 32 FMA)
#pragma unroll
    for (int q = 0; q < 16; ++q) {
      const int oa = (((q & 7) ^ tm) | (q & 8)) << 2;
      const int ob = (((q & 7) ^ tn) | (q & 8)) << 2;
      float4 a0 = *(const float4*)&As[cur][rA][oa];
      float4 a1 = *(const float4*)&As[cur][rA + 8][oa];
      float4 b0 = *(const float4*)&Bs[cur][rB + 0][ob];
      float4 b1 = *(const float4*)&Bs[cur][rB + 1][ob];
      float4 b2 = *(const float4*)&Bs[cur][rB + 2][ob];
      float4 b3 = *(const float4*)&Bs[cur][rB + 3][ob];
      acc[0][0] = fmaf(a0.x, b0.x, acc[0][0]);
      acc[0][0] = fmaf(a0.y, b0.y, acc[0][0]);
      acc[0][0] = fmaf(a0.z, b0.z, acc[0][0]);
      acc[0][0] = fmaf(a0.w, b0.w, acc[0][0]);
      acc[0][1] = fmaf(a0.x, b1.x, acc[0][1]);
      acc[0][1] = fmaf(a0.y, b1.y, acc[0][1]);
      acc[0][1] = fmaf(a0.z, b1.z, acc[0][1]);
      acc[0][1] = fmaf(a0.w, b1.w, acc[0][1]);
      acc[0][2] = fmaf(a0.x, b2.x, acc[0][2]);
      acc[0][2] = fmaf(a0.y, b2.y, acc[0][2]);
      acc[0][2] = fmaf(a0.z, b2.z, acc[0][2]);
      acc[0][2] = fmaf(a0.w, b2.w, acc[0][2]);
      acc[0][3] = fmaf(a0.x, b3.x, acc[0][3]);
      acc[0][3] = fmaf(a0.y, b3.y, acc[0][3]);
      acc[0][3] = fmaf(a0.z, b3.z, acc[0][3]);
      acc[0][3] = fmaf(a0.w, b3.w, acc[0][3]);
      acc[1][0] = fmaf(a1.x, b0.x, acc[1][0]);
      acc[1][0] = fmaf(a1.y, b0.y, acc[1][0]);
      acc[1][0] = fmaf(a1.z, b0.z, acc[1][0]);
      acc[1][0] = fmaf(a1.w, b0.w, acc[1][0]);
      acc[1][1] = fmaf(a1.x, b1.x, acc[1][1]);
      acc[1][1] = fmaf(a1.y, b1.y, acc[1][1]);
      acc[1][1] = fmaf(a1.z, b1.z, acc[1][1]);
      acc[1][1] = fmaf(a1.w, b1.w, acc[1][1]);
      acc[1][2] = fmaf(a1.x, b2.x, acc[1][2]);
      acc[1][2] = fmaf(a1.y, b2.y, acc[1][2]);
      acc[1][2] = fmaf(a1.z, b2.z, acc[1][2]);
      acc[1][2] = fmaf(a1.w, b2.w, acc[1][2]);
      acc[1][3] = fmaf(a1.x, b3.x, acc[1][3]);
      acc[1][3] = fmaf(a1.y, b3.y, acc[1][3]);
      acc[1][3] = fmaf(a1.z, b3.z, acc[1][3]);
      acc[1][3] = fmaf(a1.w, b3.w, acc[1][3]);
    }
  }
  __syncthreads();
  // final colsum flush (chunk NCH-1 lives in red[1])
  if (tid < 64) {
    float v = red[1][0][tid] + red[1][1][tid] + red[1][2][tid] + red[1][3][tid];
    csP[(size_t)blockIdx.x * HD + (NCH - 1) * KC + tid] = v;
  }
  // logits [t][e], coalesced float4 stores
  const int tA = t0 + rA;
  *(float4*)&logits[(size_t)tA * NE + rB] =
      make_float4(acc[0][0], acc[0][1], acc[0][2], acc[0][3]);
  *(float4*)&logits[(size_t)(tA + 8) * NE + rB] =
      make_float4(acc[1][0], acc[1][1], acc[1][2], acc[1][3]);
}

// ---------------------------------------------------------------------------
// K1b: colsum[k] = sum over 512 blocks (fixed order, deterministic).
// ---------------------------------------------------------------------------
__global__ __launch_bounds__(256) void k_reduce_cs(const float* __restrict__ csP,
                                                   float* __restrict__ colsum) {
  __shared__ float rr[4][64];
  const int tid = threadIdx.x;
  const int k = blockIdx.x * 64 + (tid & 63);
  const int part = tid >> 6;
  float s = 0.f;
  for (int b = part * 128; b < part * 128 + 128; ++b)
    s += csP[(size_t)b * HD + k];
  rr[part][tid & 63] = s;
  __syncthreads();
  if (tid < 64)
    colsum[blockIdx.x * 64 + tid] = rr[0][tid] + rr[1][tid] + rr[2][tid] + rr[3][tid];
}

// ---------------------------------------------------------------------------
// K2a: h = relu(cap_w1 @ mean_h + b1), one block per output row.
// ---------------------------------------------------------------------------
__global__ __launch_bounds__(256) void k_cap1(const float* __restrict__ w1,
                                              const float* __restrict__ b1,
                                              const float* __restrict__ colsum,
                                              float* __restrict__ h) {
  const int row = blockIdx.x;
  const int tid = threadIdx.x;
  const float invB = 1.0f / 16384.0f;
  const float* wr = w1 + (size_t)row * HD;
  float4 a0 = *(const float4*)(wr + tid * 4);
  float4 a1 = *(const float4*)(wr + 1024 + tid * 4);
  float4 c0 = *(const float4*)(colsum + tid * 4);
  float4 c1 = *(const float4*)(colsum + 1024 + tid * 4);
  float s = a0.x * (c0.x * invB) + a0.y * (c0.y * invB) +
            a0.z * (c0.z * invB) + a0.w * (c0.w * invB) +
            a1.x * (c1.x * invB) + a1.y * (c1.y * invB) +
            a1.z * (c1.z * invB) + a1.w * (c1.w * invB);
#pragma unroll
  for (int off = 32; off; off >>= 1) s += __shfl_down(s, off);
  __shared__ float wsum[4];
  if ((tid & 63) == 0) wsum[tid >> 6] = s;
  __syncthreads();
  if (tid == 0) {
    float t = wsum[0] + wsum[1] + wsum[2] + wsum[3] + b1[row];
    h[row] = fmaxf(t, 0.f);
  }
}

// ---------------------------------------------------------------------------
// K2b+c fused: cap_logits = cap_w2 @ h + b2, softmax, clip, capacity.
// ---------------------------------------------------------------------------
__global__ __launch_bounds__(256) void k_caphead(const float* __restrict__ w2,
                                                 const float* __restrict__ b2,
                                                 const float* __restrict__ h,
                                                 int* __restrict__ cap) {
  __shared__ float clS[64];
  const int tid = threadIdx.x;
  const int e = tid >> 2, part = tid & 3;
  const float* wr = w2 + (size_t)e * HQ + part * 128;
  const float* hp = h + part * 128;
  float s = 0.f;
#pragma unroll
  for (int i = 0; i < 32; ++i) {
    float4 a = *(const float4*)(wr + i * 4);
    float4 hv = *(const float4*)(hp + i * 4);
    s += a.x * hv.x + a.y * hv.y + a.z * hv.z + a.w * hv.w;
  }
  s += __shfl_down(s, 1);
  s += __shfl_down(s, 2);
  if (part == 0) clS[e] = s + b2[e];
  __syncthreads();
  if (tid < 64) {
    float l = clS[tid];
    float m = l;
#pragma unroll
    for (int off = 1; off < 64; off <<= 1) m = fmaxf(m, __shfl_xor(m, off));
    float ex = expf(l - m);
    float sum = ex;
#pragma unroll
    for (int off = 1; off < 64; off <<= 1) sum += __shfl_xor(sum, off);
    float wgt = ex / sum;
    float cf = 1.25f + (wgt - 0.5f) * 1.0f;
    cf = fminf(fmaxf(cf, 1.0f), 2.0f);
    cap[tid] = (int)floorf(16384.0f * cf / 64.0f);
  }
}

// ---------------------------------------------------------------------------
// K3a: per-token softmax (reads logits [t][e] from d_out), writes probsT
// [e][t] via LDS transpose; entropy via int64 fixed-point atomic.
// ---------------------------------------------------------------------------
__global__ __launch_bounds__(256) void k_softmax(const float* __restrict__ logits,
                                                 float* __restrict__ probsT,
                                                 unsigned long long* __restrict__ ent) {
  __shared__ float tpT[64][65];
  __shared__ float sw[4];
  const int tid = threadIdx.x;
  const int lane = tid & 63;
  const int wv = tid >> 6;
  const int t0 = blockIdx.x * 64;
  const int tt = tid >> 2, q = tid & 3;
  const float* lr = logits + (size_t)(t0 + tt) * NE + q * 16;
  float4 v0 = *(const float4*)(lr);
  float4 v1 = *(const float4*)(lr + 4);
  float4 v2 = *(const float4*)(lr + 8);
  float4 v3 = *(const float4*)(lr + 12);
  float p[16] = {v0.x, v0.y, v0.z, v0.w, v1.x, v1.y, v1.z, v1.w,
                 v2.x, v2.y, v2.z, v2.w, v3.x, v3.y, v3.z, v3.w};
  float m = p[0];
#pragma unroll
  for (int i = 1; i < 16; ++i) m = fmaxf(m, p[i]);
  m = fmaxf(m, __shfl_xor(m, 1));
  m = fmaxf(m, __shfl_xor(m, 2));
  float s = 0.f;
#pragma unroll
  for (int i = 0; i < 16; ++i) { p[i] = expf(p[i] - m); s += p[i]; }
  s += __shfl_xor(s, 1);
  s += __shfl_xor(s, 2);
  const float inv = 1.0f / s;
  float el = 0.f;
#pragma unroll
  for (int i = 0; i < 16; ++i) {
    float pp = p[i] * inv;
    p[i] = pp;
    el += pp * logf(pp + 1e-8f);
  }
  el += __shfl_xor(el, 1);
  el += __shfl_xor(el, 2);
#pragma unroll
  for (int i = 0; i < 16; ++i) tpT[q * 16 + i][tt] = p[i];
  float ew = (q == 0) ? el : 0.f;
#pragma unroll
  for (int off = 4; off < 64; off <<= 1) ew += __shfl_xor(ew, off);
  if (lane == 0) sw[wv] = ew;
  __syncthreads();
  if (tid == 0) {
    float bt = sw[0] + sw[1] + sw[2] + sw[3];
    atomicAdd(ent, (unsigned long long)(long long)__float2ll_rn(bt * ESCALE));
  }
  const int er = tid >> 6, tl = tid & 63;
#pragma unroll
  for (int pass = 0; pass < 16; ++pass) {
    const int e = pass * 4 + er;
    probsT[(size_t)e * TOK + t0 + tl] = tpT[e][tl];
  }
}

// ---------------------------------------------------------------------------
// K3b: per-expert exact k-th largest prob: 3-pass radix select (2048-bin
// LDS hist, uint4 loads, parallel suffix scan), 512 thr, 1 block/expert.
// ---------------------------------------------------------------------------
__global__ __launch_bounds__(STB) void k_selthr(const float* __restrict__ probsT,
                                                const int* __restrict__ cap,
                                                unsigned* __restrict__ thrT,
                                                int* __restrict__ cutoff) {
  const int e = blockIdx.x, tid = threadIdx.x;
  const uint4* col4 = (const uint4*)(probsT + (size_t)e * TOK);
  const unsigned* col = (const unsigned*)(probsT + (size_t)e * TOK);
  __shared__ unsigned hist[2048];
  __shared__ int wsfx[STB];
  __shared__ unsigned sh_pref;
  __shared__ int sh_rem;
  __shared__ int sred[8], sgt[8], seq2[8];
  const int k = cap[e];
  unsigned prefix = 0, pmask = 0;
  int rem = k;
#pragma unroll
  for (int pass = 0; pass < 3; ++pass) {
    const int shift = (pass == 0) ? 21 : (pass == 1) ? 10 : 0;
    const int nb = (pass == 2) ? 1024 : 2048;
    const unsigned bmask = nb - 1;
    for (int i = tid; i < nb; i += STB) hist[i] = 0;
    __syncthreads();
    for (int it = 0; it < TOK / (4 * STB); ++it) {
      uint4 v = col4[it * STB + tid];
      if ((v.x & pmask) == prefix) atomicAdd(&hist[(v.x >> shift) & bmask], 1u);
      if ((v.y & pmask) == prefix) atomicAdd(&hist[(v.y >> shift) & bmask], 1u);
      if ((v.z & pmask) == prefix) atomicAdd(&hist[(v.z >> shift) & bmask], 1u);
      if ((v.w & pmask) == prefix) atomicAdd(&hist[(v.w >> shift) & bmask], 1u);
    }
    __syncthreads();
    const int cs = nb / STB;
    const int base = tid * cs;
    int s = 0;
    for (int m2 = 0; m2 < cs; ++m2) s += (int)hist[base + m2];
    wsfx[tid] = s;
    __syncthreads();
    for (int off = 1; off < STB; off <<= 1) {
      int v = (tid + off < STB) ? wsfx[tid + off] : 0;
      __syncthreads();
      wsfx[tid] += v;
      __syncthreads();
    }
    int r = (tid < STB - 1) ? wsfx[tid + 1] : 0;
    for (int m2 = cs - 1; m2 >= 0; --m2) {
      int rb = r + (int)hist[base + m2];
      if (rb >= rem && r < rem) {
        sh_pref = prefix | ((unsigned)(base + m2) << shift);
        sh_rem = rem - r;
      }
      r = rb;
    }
    __syncthreads();
    prefix = sh_pref;
    rem = sh_rem;
    pmask |= bmask << shift;
    __syncthreads();
  }
  const unsigned T = prefix;
  int lgt = 0, leq = 0;
  for (int it = 0; it < TOK / (4 * STB); ++it) {
    uint4 v = col4[it * STB + tid];
    lgt += (v.x > T) + (v.y > T) + (v.z > T) + (v.w > T);
    leq += (v.x == T) + (v.y == T) + (v.z == T) + (v.w == T);
  }
#pragma unroll
  for (int off = 32; off; off >>= 1) {
    lgt += __shfl_down(lgt, off);
    leq += __shfl_down(leq, off);
  }
  if ((tid & 63) == 0) { sgt[tid >> 6] = lgt; seq2[tid >> 6] = leq; }
  __syncthreads();
  int c_gt = 0, c_eq = 0;
#pragma unroll
  for (int i = 0; i < 8; ++i) { c_gt += sgt[i]; c_eq += seq2[i]; }
  const int n_allowed = k - c_gt;
  int cut;
  if (n_allowed <= 0) {
    cut = -1;
  } else if (c_eq <= n_allowed) {
    cut = 0x7fffffff;
  } else {
    int lo = 0, hi = TOK - 1;
    while (lo < hi) {
      const int mid = (lo + hi) >> 1;
      int c = 0;
      for (int i = tid; i <= mid; i += STB) c += (col[i] == T);
#pragma unroll
      for (int off = 32; off; off >>= 1) c += __shfl_down(c, off);
      __syncthreads();
      if ((tid & 63) == 0) sred[tid >> 6] = c;
      __syncthreads();
      int cnt = 0;
#pragma unroll
      for (int i = 0; i < 8; ++i) cnt += sred[i];
      if (cnt >= n_allowed) hi = mid; else lo = mid + 1;
    }
    cut = lo;
  }
  if (tid == 0) { thrT[e] = T; cutoff[e] = cut; }
}

// ---------------------------------------------------------------------------
// K3c: per-token selection + weight + entropy finalize.
// ---------------------------------------------------------------------------
__global__ __launch_bounds__(256) void k_final(const float* __restrict__ probsT,
                                               const unsigned* __restrict__ thrT,
                                               const int* __restrict__ cutoff,
                                               const unsigned long long* __restrict__ ent,
                                               float* __restrict__ out_sel,
                                               float* __restrict__ out_w,
                                               float* __restrict__ out_ent) {
  __shared__ float tp[64][65];
  __shared__ unsigned sT[64];
  __shared__ int sC[64];
  const int tid = threadIdx.x;
  const int t0 = blockIdx.x * 64;
  if (tid < 64) { sT[tid] = thrT[tid]; sC[tid] = cutoff[tid]; }
  const int er = tid >> 6, tl2 = tid & 63;
#pragma unroll
  for (int pass = 0; pass < 16; ++pass) {
    const int e = pass * 4 + er;
    tp[e][tl2] = probsT[(size_t)e * TOK + t0 + tl2];
  }
  __syncthreads();
  const int tl = tid >> 2, q = tid & 3;
  const int t_abs = t0 + tl;
  int best = -1;
  float bw = 0.f;
  for (int i = 15; i >= 0; --i) {
    const int e = q * 16 + i;
    const float p = tp[e][tl];
    const unsigned v = __float_as_uint(p);
    const unsigned T = sT[e];
    if (v > T || (v == T && t_abs <= sC[e])) { best = e; bw = p; break; }
  }
#pragma unroll
  for (int off = 1; off <= 2; off <<= 1) {
    const int b2 = __shfl_xor(best, off);
    const float w2 = __shfl_xor(bw, off);
    if (b2 > best) { best = b2; bw = w2; }
  }
  if (q == 0) {
    out_sel[t_abs] = (float)(best >= 0 ? best : 0);
    out_w[t_abs] = (best >= 0 ? bw : 0.0f);
  }
  if (blockIdx.x == 0 && tid == 0)
    out_ent[0] = -((float)(long long)ent[0] * (1.0f / ESCALE)) / 16384.0f;
}

// ---------------------------------------------------------------------------
extern "C" void kernel_launch(void* const* d_in, const int* in_sizes, int n_in,
                              void* d_out, int out_size, void* d_ws, size_t ws_size,
                              hipStream_t stream) {
  (void)in_sizes; (void)n_in; (void)out_size; (void)ws_size;
  const float* hid = (const float*)d_in[0];
  const float* rw  = (const float*)d_in[1];
  const float* w1  = (const float*)d_in[2];
  const float* b1  = (const float*)d_in[3];
  const float* w2  = (const float*)d_in[4];
  const float* b2  = (const float*)d_in[5];
  float* out = (float*)d_out;
  float* logits  = out;
  float* out_sel = out + (size_t)TOK * NE;
  float* out_w   = out_sel + TOK;
  float* out_ent = out_w + TOK;
  char* ws = (char*)d_ws;
  float*              colsum = (float*)(ws + 0);        // 2048 f32
  unsigned long long* ent    = (unsigned long long*)(ws + 8192);
  float*              h      = (float*)(ws + 8448);     // 512 f32
  int*                cap    = (int*)(ws + 10752);
  unsigned*           thr    = (unsigned*)(ws + 11008);
  int*                cut    = (int*)(ws + 11264);
  // region X (4 MiB): csP (512 blocks x 2048 f32; K1 -> K1b) then probsT
  // (4 MiB; K3a -> K3b/K3c). Stream-ordered reuse, no overlap.
  float*              csP    = (float*)(ws + 16384);
  float*              probsT = (float*)(ws + 16384);

  hipMemsetAsync(ent, 0, 8, stream);
  hipLaunchKernelGGL(k_router, dim3(TOK / 32), dim3(256), 0, stream,
                     hid, rw, logits, csP);
  hipLaunchKernelGGL(k_reduce_cs, dim3(HD / 64), dim3(256), 0, stream, csP, colsum);
  hipLaunchKernelGGL(k_cap1, dim3(HQ), dim3(256), 0, stream, w1, b1, colsum, h);
  hipLaunchKernelGGL(k_caphead, dim3(1), dim3(256), 0, stream, w2, b2, h, cap);
  hipLaunchKernelGGL(k_softmax, dim3(TOK / 64), dim3(256), 0, stream,
                     logits, probsT, ent);
  hipLaunchKernelGGL(k_selthr, dim3(NE), dim3(STB), 0, stream, probsT, cap, thr, cut);
  hipLaunchKernelGGL(k_final, dim3(TOK / 64), dim3(256), 0, stream,
                     probsT, thr, cut, ent, out_sel, out_w, out_ent);
}